// Round 13
// baseline (411.070 us; speedup 1.0000x reference)
//
#include <hip/hip_runtime.h>
#include <hip/hip_bf16.h>
#include <stdint.h>

#define NN   100000
#define ICH  256
#define HID  128
#define OUTF 64

typedef float  f32x4  __attribute__((ext_vector_type(4)));
typedef __bf16 bf16x8 __attribute__((ext_vector_type(8)));

__device__ __forceinline__ float bf2f(uint16_t u){
  union { uint32_t i; float f; } v; v.i = ((uint32_t)u) << 16; return v.f;
}
__device__ __forceinline__ uint16_t f2bf(float f){
  union { float f; uint32_t i; } v; v.f = f;
  uint32_t i = v.i;
  return (uint16_t)((i + 0x7FFFu + ((i >> 16) & 1u)) >> 16);
}
__device__ __forceinline__ uint32_t pack2(float a, float b){
  return (uint32_t)f2bf(a) | ((uint32_t)f2bf(b) << 16);
}

// Fused CSR build: edges sorted by src. rp[i] + r[i] = 1/(deg_i+1).
__global__ void k_csr(const int* __restrict__ row, int E, int n,
                      int* __restrict__ rp, float* __restrict__ r){
  int i = blockIdx.x * blockDim.x + threadIdx.x;
  if (i > n) return;
  int lo = 0, hi = E;
  while (lo < hi){
    int mid = (lo + hi) >> 1;
    if (row[mid] < i) lo = mid + 1; else hi = mid;
  }
  rp[i] = lo;
  if (i < n){
    int lo2 = lo, hi2 = E;
    while (lo2 < hi2){
      int mid = (lo2 + hi2) >> 1;
      if (row[mid] < i + 1) lo2 = mid + 1; else hi2 = mid;
    }
    r[i] = 1.0f / (float)(lo2 - lo + 1);
  }
}

// bf16-transpose weights: W1T/W2T [l][n][k], Wl1T [n][k] (k<256), Wl2T [n][k]
__global__ void k_wprep(const float* __restrict__ W1, const float* __restrict__ W2,
                        const float* __restrict__ Wl1, const float* __restrict__ Wl2,
                        uint16_t* __restrict__ W1T, uint16_t* __restrict__ W2T,
                        uint16_t* __restrict__ Wl1T, uint16_t* __restrict__ Wl2T){
  int idx = blockIdx.x * blockDim.x + threadIdx.x;
  if (idx < 4 * 128 * 128){
    int l = idx >> 14, rem = idx & 16383, n = rem >> 7, k = rem & 127;
    W1T[idx] = f2bf(W1[l * 16384 + k * 128 + n]);
    W2T[idx] = f2bf(W2[l * 16384 + k * 128 + n]);
  }
  if (idx < 128 * 256){
    int n = idx >> 8, k = idx & 255;
    Wl1T[idx] = f2bf(Wl1[k * 128 + n]);
  }
  if (idx < 64 * 128){
    int n = idx >> 7, k = idx & 127;
    Wl2T[idx] = f2bf(Wl2[k * 64 + n]);
  }
}

// h = relu(x @ W_lin1 + b) via MFMA. 64-node tile, wave w owns cols [32w,32w+32).
__launch_bounds__(256)
__global__ void k_lin1m(const float* __restrict__ x, const uint16_t* __restrict__ Wl1T,
                        const float* __restrict__ b, uint16_t* __restrict__ h){
  __shared__ __align__(16) uint16_t Xs[64][264];   // 256 + 8 pad
  const int tid = threadIdx.x;
  const int node0 = blockIdx.x * 64;
  const int wv = tid >> 6, lane = tid & 63, lr = lane & 15, lg = lane >> 4;

  #pragma unroll
  for (int i = 0; i < 16; ++i){
    int fi = tid + i * 256;
    int rrow = fi >> 6, c4 = (fi & 63) * 4;
    int nd = node0 + rrow;
    float4 f = (nd < NN) ? *(const float4*)(x + (size_t)nd * ICH + c4)
                         : make_float4(0.f, 0.f, 0.f, 0.f);
    *(uint2*)&Xs[rrow][c4] = make_uint2(pack2(f.x, f.y), pack2(f.z, f.w));
  }
  __syncthreads();

  bf16x8 bfr[2][8];
  #pragma unroll
  for (int n2 = 0; n2 < 2; ++n2){
    const int n = (2 * wv + n2) * 16 + lr;
    const uint16_t* bp = Wl1T + (size_t)n * 256 + lg * 8;
    #pragma unroll
    for (int ks = 0; ks < 8; ++ks)
      bfr[n2][ks] = __builtin_bit_cast(bf16x8, *(const uint4*)(bp + ks * 32));
  }
  float bias[2] = {b[(2 * wv + 0) * 16 + lr], b[(2 * wv + 1) * 16 + lr]};

  #pragma unroll
  for (int rt = 0; rt < 4; ++rt){
    const int row = rt * 16 + lr;
    bf16x8 af[8];
    #pragma unroll
    for (int ks = 0; ks < 8; ++ks)
      af[ks] = __builtin_bit_cast(bf16x8, *(const uint4*)&Xs[row][ks * 32 + lg * 8]);
    #pragma unroll
    for (int n2 = 0; n2 < 2; ++n2){
      f32x4 d = (f32x4){0.f, 0.f, 0.f, 0.f};
      #pragma unroll
      for (int ks = 0; ks < 8; ++ks)
        d = __builtin_amdgcn_mfma_f32_16x16x32_bf16(af[ks], bfr[n2][ks], d, 0, 0, 0);
      const int ncol = (2 * wv + n2) * 16 + lr;
      #pragma unroll
      for (int q = 0; q < 4; ++q){
        int nd = node0 + rt * 16 + lg * 4 + q;
        if (nd < NN){
          float v = d[q] + bias[n2];
          h[(size_t)nd * HID + ncol] = f2bf(v > 0.f ? v : 0.f);
        }
      }
    }
  }
}

// spmmA v3: wave = 1 node, 4 edge-groups x 16 lanes, 16B/lane row loads.
// UNIFORM trip counts (kmax = ceil4(cnt)) so every __shfl executes at full
// exec (R12 bug: bpermute from exec-masked lanes at divergent loop tails).
// Invalid k masked by weight w in {0,1}; invalid loads hit row 0 harmlessly.
__launch_bounds__(256)
__global__ void k_spmmA(const int* __restrict__ col, const int* __restrict__ rp,
                        const float* __restrict__ r, const uint32_t* __restrict__ h,
                        uint32_t* __restrict__ P, uint32_t* __restrict__ T1,
                        uint32_t* __restrict__ T2){
  int wid  = (blockIdx.x * blockDim.x + threadIdx.x) >> 6;
  int lane = threadIdx.x & 63;
  if (wid >= NN) return;
  const int g  = lane >> 4;
  const uint32_t co = (uint32_t)(lane & 15) << 2;   // uint offset within row
  int e0 = rp[wid], e1 = rp[wid + 1];

  float s0[8], s1[8], s2[8];
  #pragma unroll
  for (int u = 0; u < 8; ++u){ s0[u] = 0.f; s1[u] = 0.f; s2[u] = 0.f; }

  for (int base = e0; base < e1; base += 64){
    int tot = e1 - base;
    int cnt = tot < 64 ? tot : 64;
    int jv  = (lane < cnt) ? col[base + lane] : 0;
    int rvb = (lane < cnt) ? __builtin_bit_cast(int, r[jv]) : 0;
    int kmax = (cnt + 3) & ~3;          // wave-uniform; trips identical per group

    int k = g;
    int   jr = __shfl(jv, k);           // full exec
    float rr = __builtin_bit_cast(float, __shfl(rvb, k));
    float wA = (k < cnt) ? 1.f : 0.f;
    uint32_t jA = (k < cnt) ? (uint32_t)jr : 0u;
    float rA = rr * wA;
    uint4 A = *(const uint4*)(h + (jA << 6) + co);

    for (k = g + 4; k < kmax; k += 4){  // kmax/4-1 iterations for EVERY group
      int   jr2 = __shfl(jv, k);        // full exec
      float rr2 = __builtin_bit_cast(float, __shfl(rvb, k));
      float wB = (k < cnt) ? 1.f : 0.f;
      uint32_t jB = (k < cnt) ? (uint32_t)jr2 : 0u;
      float rB = rr2 * wB;
      uint4 B = *(const uint4*)(h + (jB << 6) + co);

      float r2 = rA * rA;
      const uint32_t* au = (const uint32_t*)&A;
      #pragma unroll
      for (int u = 0; u < 4; ++u){
        float x0 = __builtin_bit_cast(float, au[u] << 16);
        float x1 = __builtin_bit_cast(float, au[u] & 0xFFFF0000u);
        s0[2*u]   = fmaf(wA, x0, s0[2*u]);   s0[2*u+1] = fmaf(wA, x1, s0[2*u+1]);
        s1[2*u]   = fmaf(rA, x0, s1[2*u]);   s1[2*u+1] = fmaf(rA, x1, s1[2*u+1]);
        s2[2*u]   = fmaf(r2, x0, s2[2*u]);   s2[2*u+1] = fmaf(r2, x1, s2[2*u+1]);
      }
      A = B; wA = wB; rA = rB;
    }
    {
      float r2 = rA * rA;
      const uint32_t* au = (const uint32_t*)&A;
      #pragma unroll
      for (int u = 0; u < 4; ++u){
        float x0 = __builtin_bit_cast(float, au[u] << 16);
        float x1 = __builtin_bit_cast(float, au[u] & 0xFFFF0000u);
        s0[2*u]   = fmaf(wA, x0, s0[2*u]);   s0[2*u+1] = fmaf(wA, x1, s0[2*u+1]);
        s1[2*u]   = fmaf(rA, x0, s1[2*u]);   s1[2*u+1] = fmaf(rA, x1, s1[2*u+1]);
        s2[2*u]   = fmaf(r2, x0, s2[2*u]);   s2[2*u+1] = fmaf(r2, x1, s2[2*u+1]);
      }
    }
  }

  // cross-group reduce (groups at lane^16, lane^32) — full exec, converged
  #pragma unroll
  for (int u = 0; u < 8; ++u){
    s0[u] += __shfl_xor(s0[u], 16); s0[u] += __shfl_xor(s0[u], 32);
    s1[u] += __shfl_xor(s1[u], 16); s1[u] += __shfl_xor(s1[u], 32);
    s2[u] += __shfl_xor(s2[u], 16); s2[u] += __shfl_xor(s2[u], 32);
  }
  if (g == 0){
    size_t o = ((size_t)wid << 6) + co;
    *(uint4*)(P  + o) = make_uint4(pack2(s0[0], s0[1]), pack2(s0[2], s0[3]),
                                   pack2(s0[4], s0[5]), pack2(s0[6], s0[7]));
    *(uint4*)(T1 + o) = make_uint4(pack2(s1[0], s1[1]), pack2(s1[2], s1[3]),
                                   pack2(s1[4], s1[5]), pack2(s1[6], s1[7]));
    *(uint4*)(T2 + o) = make_uint4(pack2(s2[0], s2[1]), pack2(s2[2], s2[3]),
                                   pack2(s2[4], s2[5]), pack2(s2[6], s2[7]));
  }
}

// spmmB v3: same uniform-trip structure; Q1 = S(r.P), Q2 = S(r^2.P)
__launch_bounds__(256)
__global__ void k_spmmB(const int* __restrict__ col, const int* __restrict__ rp,
                        const float* __restrict__ r, const uint32_t* __restrict__ Pm,
                        uint32_t* __restrict__ Q1, uint32_t* __restrict__ Q2){
  int wid  = (blockIdx.x * blockDim.x + threadIdx.x) >> 6;
  int lane = threadIdx.x & 63;
  if (wid >= NN) return;
  const int g  = lane >> 4;
  const uint32_t co = (uint32_t)(lane & 15) << 2;
  int e0 = rp[wid], e1 = rp[wid + 1];

  float s1[8], s2[8];
  #pragma unroll
  for (int u = 0; u < 8; ++u){ s1[u] = 0.f; s2[u] = 0.f; }

  for (int base = e0; base < e1; base += 64){
    int tot = e1 - base;
    int cnt = tot < 64 ? tot : 64;
    int jv  = (lane < cnt) ? col[base + lane] : 0;
    int rvb = (lane < cnt) ? __builtin_bit_cast(int, r[jv]) : 0;
    int kmax = (cnt + 3) & ~3;

    int k = g;
    int   jr = __shfl(jv, k);
    float rr = __builtin_bit_cast(float, __shfl(rvb, k));
    float wA = (k < cnt) ? 1.f : 0.f;
    uint32_t jA = (k < cnt) ? (uint32_t)jr : 0u;
    float rA = rr * wA;
    uint4 A = *(const uint4*)(Pm + (jA << 6) + co);

    for (k = g + 4; k < kmax; k += 4){
      int   jr2 = __shfl(jv, k);
      float rr2 = __builtin_bit_cast(float, __shfl(rvb, k));
      float wB = (k < cnt) ? 1.f : 0.f;
      uint32_t jB = (k < cnt) ? (uint32_t)jr2 : 0u;
      float rB = rr2 * wB;
      uint4 B = *(const uint4*)(Pm + (jB << 6) + co);

      float r2 = rA * rA;
      const uint32_t* au = (const uint32_t*)&A;
      #pragma unroll
      for (int u = 0; u < 4; ++u){
        float x0 = __builtin_bit_cast(float, au[u] << 16);
        float x1 = __builtin_bit_cast(float, au[u] & 0xFFFF0000u);
        s1[2*u] = fmaf(rA, x0, s1[2*u]);   s1[2*u+1] = fmaf(rA, x1, s1[2*u+1]);
        s2[2*u] = fmaf(r2, x0, s2[2*u]);   s2[2*u+1] = fmaf(r2, x1, s2[2*u+1]);
      }
      A = B; rA = rB;
    }
    {
      float r2 = rA * rA;
      const uint32_t* au = (const uint32_t*)&A;
      #pragma unroll
      for (int u = 0; u < 4; ++u){
        float x0 = __builtin_bit_cast(float, au[u] << 16);
        float x1 = __builtin_bit_cast(float, au[u] & 0xFFFF0000u);
        s1[2*u] = fmaf(rA, x0, s1[2*u]);   s1[2*u+1] = fmaf(rA, x1, s1[2*u+1]);
        s2[2*u] = fmaf(r2, x0, s2[2*u]);   s2[2*u+1] = fmaf(r2, x1, s2[2*u+1]);
      }
    }
  }

  #pragma unroll
  for (int u = 0; u < 8; ++u){
    s1[u] += __shfl_xor(s1[u], 16); s1[u] += __shfl_xor(s1[u], 32);
    s2[u] += __shfl_xor(s2[u], 16); s2[u] += __shfl_xor(s2[u], 32);
  }
  if (g == 0){
    size_t o = ((size_t)wid << 6) + co;
    *(uint4*)(Q1 + o) = make_uint4(pack2(s1[0], s1[1]), pack2(s1[2], s1[3]),
                                   pack2(s1[4], s1[5]), pack2(s1[6], s1[7]));
    *(uint4*)(Q2 + o) = make_uint4(pack2(s2[0], s2[1]), pack2(s2[2], s2[3]),
                                   pack2(s2[4], s2[5]), pack2(s2[6], s2[7]));
  }
}

// Epilogue v8 (unchanged): epi5 dataflow + LDS double-buffer phases.
__launch_bounds__(512)
__global__ void k_epi8(const uint32_t* __restrict__ h,  const uint32_t* __restrict__ P,
                       const uint32_t* __restrict__ T1, const uint32_t* __restrict__ T2,
                       const uint32_t* __restrict__ Q1, const uint32_t* __restrict__ Q2,
                       const float* __restrict__ r,
                       const uint16_t* __restrict__ W1T, const uint16_t* __restrict__ W2T,
                       const uint16_t* __restrict__ Wl2T, const float* __restrict__ b2,
                       float* __restrict__ out){
  __shared__ __align__(16) uint32_t Mu[2][2][64][68];  // [buf][m][row][chunk]
  const int tid = threadIdx.x;
  const int node0 = blockIdx.x * 64;
  const int wv = tid >> 6, lane = tid & 63, lr = lane & 15, lg = lane >> 4;

  const int nb = tid >> 3;
  const int qc = tid & 7;
  const int nd = node0 + nb;
  const int rn = nd < NN ? nd : NN - 1;
  const float rv = r[rn];
  const size_t ub = (size_t)rn * 64;
  const int cc2[2] = {qc, qc + 8};

  f32x4 acc[4];
  #pragma unroll
  for (int rt = 0; rt < 4; ++rt) acc[rt] = (f32x4){0.f, 0.f, 0.f, 0.f};

  auto mfma_phase = [&](int buf, const uint16_t* Wa, const uint16_t* Wb){
    __builtin_amdgcn_s_setprio(1);
    #pragma unroll
    for (int m = 0; m < 2; ++m){
      const uint16_t* bp = (m ? Wb : Wa) + (size_t)(wv * 16 + lr) * 128 + lg * 8;
      bf16x8 bfr[4];
      #pragma unroll
      for (int ks = 0; ks < 4; ++ks)
        bfr[ks] = __builtin_bit_cast(bf16x8, *(const uint4*)(bp + ks * 32));
      #pragma unroll
      for (int rt = 0; rt < 4; ++rt){
        const int row = rt * 16 + lr;
        f32x4 d = (f32x4){0.f, 0.f, 0.f, 0.f};
        #pragma unroll
        for (int ks = 0; ks < 4; ++ks){
          bf16x8 af = __builtin_bit_cast(bf16x8,
              *(const uint4*)&Mu[buf][m][row][ks * 16 + lg * 4]);
          d = __builtin_amdgcn_mfma_f32_16x16x32_bf16(af, bfr[ks], d, 0, 0, 0);
        }
        #pragma unroll
        for (int q = 0; q < 4; ++q)
          acc[rt][q] += (d[q] > 0.f ? d[q] : 0.f);
      }
    }
    __builtin_amdgcn_s_setprio(0);
  };

  uint4 vh[2], vP[2], vT1[2], vQ1[2];
  #pragma unroll
  for (int ci = 0; ci < 2; ++ci){
    vh[ci]  = *(const uint4*)(h  + ub + cc2[ci] * 4);
    vP[ci]  = *(const uint4*)(P  + ub + cc2[ci] * 4);
    vT1[ci] = *(const uint4*)(T1 + ub + cc2[ci] * 4);
    vQ1[ci] = *(const uint4*)(Q1 + ub + cc2[ci] * 4);
  }

  // ---- build layer 0 -> buf0 ----
  #pragma unroll
  for (int ci = 0; ci < 2; ++ci){
    const uint32_t* ah = (const uint32_t*)&vh[ci];
    const uint32_t* ap = (const uint32_t*)&vP[ci];
    uint32_t o1[4], o2[4];
    #pragma unroll
    for (int w = 0; w < 4; ++w){
      float m1s[2], m2s[2];
      #pragma unroll
      for (int s = 0; s < 2; ++s){
        float hh = bf2f((uint16_t)(s ? (ah[w] >> 16) : ah[w]));
        float pp = bf2f((uint16_t)(s ? (ap[w] >> 16) : ap[w]));
        float F = rv * (pp + hh);
        m1s[s] = F; m2s[s] = hh - F;
      }
      o1[w] = pack2(m1s[0], m1s[1]);
      o2[w] = pack2(m2s[0], m2s[1]);
    }
    *(uint4*)&Mu[0][0][nb][cc2[ci] * 4] = make_uint4(o1[0], o1[1], o1[2], o1[3]);
    *(uint4*)&Mu[0][1][nb][cc2[ci] * 4] = make_uint4(o2[0], o2[1], o2[2], o2[3]);
  }
  __syncthreads();

  // ---- phase 0: MFMA(l0, buf0) || build l1 -> buf1 (+prefetch T2,Q2) ----
  mfma_phase(0, W1T, W2T);
  #pragma unroll
  for (int ci = 0; ci < 2; ++ci){
    const uint32_t* ah = (const uint32_t*)&vh[ci];
    const uint32_t* ap = (const uint32_t*)&vP[ci];
    const uint32_t* at = (const uint32_t*)&vT1[ci];
    const uint32_t* aq = (const uint32_t*)&vQ1[ci];
    uint32_t o1[4], o2[4];
    #pragma unroll
    for (int w = 0; w < 4; ++w){
      float m1s[2], m2s[2];
      #pragma unroll
      for (int s = 0; s < 2; ++s){
        float hh = bf2f((uint16_t)(s ? (ah[w] >> 16) : ah[w]));
        float pp = bf2f((uint16_t)(s ? (ap[w] >> 16) : ap[w]));
        float t1 = bf2f((uint16_t)(s ? (at[w] >> 16) : at[w]));
        float q1 = bf2f((uint16_t)(s ? (aq[w] >> 16) : aq[w]));
        float F = rv * (pp + hh);
        float G = hh - F;
        m1s[s] = rv * (pp - q1 - t1 + G);
        m2s[s] = F - rv * (q1 + t1 + F);
      }
      o1[w] = pack2(m1s[0], m1s[1]);
      o2[w] = pack2(m2s[0], m2s[1]);
    }
    *(uint4*)&Mu[1][0][nb][cc2[ci] * 4] = make_uint4(o1[0], o1[1], o1[2], o1[3]);
    *(uint4*)&Mu[1][1][nb][cc2[ci] * 4] = make_uint4(o2[0], o2[1], o2[2], o2[3]);
  }
  uint4 vT2[2], vQ2[2];
  #pragma unroll
  for (int ci = 0; ci < 2; ++ci){
    vT2[ci] = *(const uint4*)(T2 + ub + cc2[ci] * 4);
    vQ2[ci] = *(const uint4*)(Q2 + ub + cc2[ci] * 4);
  }
  __syncthreads();

  // ---- phase 1: MFMA(l1, buf1) || build l2 -> buf0 ----
  mfma_phase(1, W1T + 16384, W2T + 16384);
  #pragma unroll
  for (int ci = 0; ci < 2; ++ci){
    const uint32_t* ah = (const uint32_t*)&vh[ci];
    const uint32_t* ap = (const uint32_t*)&vP[ci];
    const uint32_t* at1 = (const uint32_t*)&vT1[ci];
    const uint32_t* at2 = (const uint32_t*)&vT2[ci];
    const uint32_t* aq2 = (const uint32_t*)&vQ2[ci];
    uint32_t o1[4], o2[4];
    #pragma unroll
    for (int w = 0; w < 4; ++w){
      float m1s[2], m2s[2];
      #pragma unroll
      for (int s = 0; s < 2; ++s){
        float hh = bf2f((uint16_t)(s ? (ah[w] >> 16) : ah[w]));
        float pp = bf2f((uint16_t)(s ? (ap[w] >> 16) : ap[w]));
        float t1 = bf2f((uint16_t)(s ? (at1[w] >> 16) : at1[w]));
        float t2 = bf2f((uint16_t)(s ? (at2[w] >> 16) : at2[w]));
        float q2 = bf2f((uint16_t)(s ? (aq2[w] >> 16) : aq2[w]));
        float omr = 1.f - rv;
        float G2 = rv * rv * pp + omr * omr * hh;
        m1s[s] = rv * (q2 + pp - 2.f * t1 + t2 + G2);
        float F2 = rv * rv * (pp + hh);
        m2s[s] = F2 - rv * (q2 + t2 + F2);
      }
      o1[w] = pack2(m1s[0], m1s[1]);
      o2[w] = pack2(m2s[0], m2s[1]);
    }
    *(uint4*)&Mu[0][0][nb][cc2[ci] * 4] = make_uint4(o1[0], o1[1], o1[2], o1[3]);
    *(uint4*)&Mu[0][1][nb][cc2[ci] * 4] = make_uint4(o2[0], o2[1], o2[2], o2[3]);
  }
  __syncthreads();

  // ---- phase 2: MFMA(l2, buf0) || build l3 -> buf1 ----
  mfma_phase(0, W1T + 2 * 16384, W2T + 2 * 16384);
  #pragma unroll
  for (int ci = 0; ci < 2; ++ci){
    const uint32_t* ah = (const uint32_t*)&vh[ci];
    const uint32_t* ap = (const uint32_t*)&vP[ci];
    uint32_t o1[4], o2[4];
    #pragma unroll
    for (int w = 0; w < 4; ++w){
      float m1s[2], m2s[2];
      #pragma unroll
      for (int s = 0; s < 2; ++s){
        float hh = bf2f((uint16_t)(s ? (ah[w] >> 16) : ah[w]));
        float pp = bf2f((uint16_t)(s ? (ap[w] >> 16) : ap[w]));
        float omr = 1.f - rv;
        float r3 = rv * rv * rv;
        m1s[s] = omr * omr * omr * hh - r3 * pp;
        m2s[s] = r3 * (pp + hh);
      }
      o1[w] = pack2(m1s[0], m1s[1]);
      o2[w] = pack2(m2s[0], m2s[1]);
    }
    *(uint4*)&Mu[1][0][nb][cc2[ci] * 4] = make_uint4(o1[0], o1[1], o1[2], o1[3]);
    *(uint4*)&Mu[1][1][nb][cc2[ci] * 4] = make_uint4(o2[0], o2[1], o2[2], o2[3]);
  }
  __syncthreads();

  // ---- phase 3: MFMA(l3, buf1) ----
  mfma_phase(1, W1T + 3 * 16384, W2T + 3 * 16384);

  // ---- lin2 ----
  uint16_t* Mb = (uint16_t*)&Mu[0][0][0][0];
  #pragma unroll
  for (int rt = 0; rt < 4; ++rt)
    #pragma unroll
    for (int q = 0; q < 4; ++q){
      int row = rt * 16 + lg * 4 + q;
      int colb = wv * 16 + lr;
      Mb[row * 136 + colb] = f2bf(acc[rt][q] * 0.125f);
    }
  __syncthreads();

  const int rt2 = wv >> 1;
  const int arow = rt2 * 16 + lr;
  bf16x8 af2[4];
  #pragma unroll
  for (int ks = 0; ks < 4; ++ks)
    af2[ks] = __builtin_bit_cast(bf16x8, *(const uint4*)&Mu[0][0][arow][ks * 16 + lg * 4]);
  #pragma unroll
  for (int ntl = 0; ntl < 2; ++ntl){
    const int nt = (wv & 1) * 2 + ntl;
    f32x4 d = (f32x4){0.f, 0.f, 0.f, 0.f};
    #pragma unroll
    for (int ks = 0; ks < 4; ++ks){
      bf16x8 bfr = __builtin_bit_cast(bf16x8,
          *(const uint4*)(Wl2T + (size_t)(nt * 16 + lr) * 128 + ks * 32 + lg * 8));
      d = __builtin_amdgcn_mfma_f32_16x16x32_bf16(af2[ks], bfr, d, 0, 0, 0);
    }
    float bias = b2[nt * 16 + lr];
    #pragma unroll
    for (int q = 0; q < 4; ++q){
      int rr = node0 + rt2 * 16 + lg * 4 + q;
      if (rr < NN) out[(size_t)rr * OUTF + nt * 16 + lr] = d[q] + bias;
    }
  }
}

extern "C" void kernel_launch(void* const* d_in, const int* in_sizes, int n_in,
                              void* d_out, int out_size, void* d_ws, size_t ws_size,
                              hipStream_t stream){
  const float* x   = (const float*)d_in[0];
  const float* Wl1 = (const float*)d_in[1];
  const float* bl1 = (const float*)d_in[2];
  const float* W1  = (const float*)d_in[3];
  const float* W2  = (const float*)d_in[4];
  const float* Wl2 = (const float*)d_in[5];
  const float* bl2 = (const float*)d_in[6];
  const int*   ei  = (const int*)d_in[7];
  int E = in_sizes[7] / 2;
  const int* rowp = ei;
  const int* colp = ei + E;

  char* ws = (char*)d_ws;
  size_t off = 0;
  auto alloc = [&](size_t bytes) -> void* {
    void* p = ws + off;
    off += (bytes + 255) & ~(size_t)255;
    return p;
  };
  const size_t MATB = (size_t)NN * HID * 2;
  uint32_t* h  = (uint32_t*)alloc(MATB);
  uint32_t* P  = (uint32_t*)alloc(MATB);
  uint32_t* T1 = (uint32_t*)alloc(MATB);
  uint32_t* T2 = (uint32_t*)alloc(MATB);
  uint32_t* Q1 = (uint32_t*)alloc(MATB);
  uint32_t* Q2 = (uint32_t*)alloc(MATB);
  float* r  = (float*)alloc((size_t)NN * 4);
  int* rp   = (int*)alloc((size_t)(NN + 1) * 4);
  uint16_t* W1T  = (uint16_t*)alloc((size_t)4 * 128 * 128 * 2);
  uint16_t* W2T  = (uint16_t*)alloc((size_t)4 * 128 * 128 * 2);
  uint16_t* Wl1T = (uint16_t*)alloc((size_t)128 * 256 * 2);
  uint16_t* Wl2T = (uint16_t*)alloc((size_t)64 * 128 * 2);

  k_wprep<<<(4 * 128 * 128 + 255) / 256, 256, 0, stream>>>(W1, W2, Wl1, Wl2,
                                                           W1T, W2T, Wl1T, Wl2T);
  k_csr<<<(NN + 1 + 255) / 256, 256, 0, stream>>>(rowp, E, NN, rp, r);
  k_lin1m<<<(NN + 63) / 64, 256, 0, stream>>>(x, Wl1T, bl1, (uint16_t*)h);
  k_spmmA<<<(NN + 3) / 4, 256, 0, stream>>>(colp, rp, r, h, P, T1, T2);
  k_spmmB<<<(NN + 3) / 4, 256, 0, stream>>>(colp, rp, r, P, Q1, Q2);
  k_epi8<<<(NN + 63) / 64, 512, 0, stream>>>(h, P, T1, T2, Q1, Q2, r,
                                             W1T, W2T, Wl2T, bl2, (float*)d_out);
}